// Round 14
// baseline (770.134 us; speedup 1.0000x reference)
//
#include <hip/hip_runtime.h>
#include <hip/hip_bf16.h>
#include <stdint.h>

// HMM batched forward, B=128, T=8192, S=65 (state 0 = bookend dead after init), V=1024.
//
// R14: Q=4 segment split with rank-1 middle reconstruction.
// Apps 0..4095 in 4 segments of 1024. Per batch, 6 runs (768 blocks total):
//   rid0: fwd S0 from alpha0 (exact)        -> F0, L0
//   rid1: fwd S1 from ones                  -> U1, L1
//   rid2: bwd S1 from ones (P^T)            -> V1 (direction only)
//   rid3: fwd S2 from ones                  -> U2, L3
//   rid4: bwd S2 from ones                  -> V2 (direction only)
//   rid5: bwd S3 from tau (exact)           -> G,  L5
// All per-app operators are strictly positive => Birkhoff contraction makes each
// 1024-app middle product rank-1 to far below f32 precision: P_seg ~ sigma U V^T
// with sigma = e^{Lfwd}/(V^T 1). Combine:
//   log L = L0+L1+L3+L5 + log(V1.F0) + log(V2.U1) + log(G.U2)
//           - log(sum V1) - log(sum V2) + tcmax
// Per-app machinery is R13's PROVEN code verbatim (asm dwordx4 depth-4 ring +
// vmcnt(27), replicated-A MFMA, stale-inv renorm, ds_bpermute rebuild).

#define HMM_B 128
#define HMM_T 8192
#define HMM_S 65
#define HMM_V 1024
#define LN2 0.6931471805599453

typedef _Float16 h8 __attribute__((ext_vector_type(8)));
typedef int    v4i __attribute__((ext_vector_type(4)));
typedef float  v4f __attribute__((ext_vector_type(4)));
typedef unsigned int uint;

// ---------------- device-global tables ----------------
__device__ __attribute__((aligned(16))) __fp16 gMtab[HMM_V * 4096];   // fused 2-step, B-frag
__device__ __attribute__((aligned(16))) __fp16 gMtabT[HMM_V * 4096];  // transposed, B-frag
__device__ __attribute__((aligned(16))) __fp16 gP1[4096];             // app-0 1-step (ET*2^10)
__device__ __attribute__((aligned(16))) float  gEmitT2[HMM_V * 64];   // [v][c*4+u] = e_v[16u+c]
__device__ float gSlog[HMM_V];
__device__ float gET[64 * 64];
__device__ __attribute__((aligned(16))) float gArow0[64];
__device__ __attribute__((aligned(16))) float gTcs2[64];  // [c*4+u] = exp(tcol[16u+c]-tcmax)
__device__ float gTcmax;
// split-scan handoff: 6 runs x 64 floats per batch + 6 logs
__device__ __attribute__((aligned(16))) float gVecs[HMM_B * 6 * 64];
__device__ double gLs[HMM_B * 6];

// frag-position: value X[i][n] (input row i, output col n) -> (r, lane, slot j)
__device__ __forceinline__ void frag_pos(int i, int n, int* r, int* lane, int* j) {
    int t = i >> 5, up = (i >> 4) & 1, g = (i & 15) >> 2, q = i & 3;
    *r = t * 4 + (n >> 4);
    *lane = g * 16 + (n & 15);
    *j = 2 * q + up;
}

// ---------------- helpers ----------------
template <int CTRL>
__device__ __forceinline__ float dpp_add(float x) {
    return x + __int_as_float(__builtin_amdgcn_update_dpp(
                   0, __float_as_int(x), CTRL, 0xF, 0xF, true));
}
#define DPP16_SUM(S)            \
    S = dpp_add<0xB1>(S);       \
    S = dpp_add<0x4E>(S);       \
    S = dpp_add<0x141>(S);      \
    S = dpp_add<0x128>(S);

__device__ __forceinline__ float fast_rcp(float x) {
#if __has_builtin(__builtin_amdgcn_rcpf)
    return __builtin_amdgcn_rcpf(x);
#else
    return 1.0f / x;
#endif
}

__device__ __forceinline__ h8 bfrag(v4i q) { return __builtin_bit_cast(h8, q); }
__device__ __forceinline__ int pkh(float a, float b) {
    return __builtin_bit_cast(int, __builtin_amdgcn_cvt_pkrtz(a, b));
}

#define MFMA16(A, B, C) __builtin_amdgcn_mfma_f32_16x16x32_f16((A), (B), (C), 0, 0, 0)

#define ISSUE_APP(TQ, EV, W, TBASE)                                               \
    {                                                                             \
        uint w_ = (W);                                                            \
        uint u_ = (uint)__builtin_amdgcn_readfirstlane((int)w_);                  \
        const __fp16* t0_ = (TBASE) + (size_t)(u_ & 0xFFFFu) * 4096u;             \
        const __fp16* t1_ = t0_ + 2048;                                           \
        const float* eb_ = gEmitT2 + (size_t)(u_ >> 16) * 64u;                    \
        asm volatile("global_load_dwordx4 %0, %9, %11\n\t"                        \
                     "global_load_dwordx4 %1, %9, %11 offset:1024\n\t"            \
                     "global_load_dwordx4 %2, %9, %11 offset:2048\n\t"            \
                     "global_load_dwordx4 %3, %9, %11 offset:3072\n\t"            \
                     "global_load_dwordx4 %4, %9, %12\n\t"                        \
                     "global_load_dwordx4 %5, %9, %12 offset:1024\n\t"            \
                     "global_load_dwordx4 %6, %9, %12 offset:2048\n\t"            \
                     "global_load_dwordx4 %7, %9, %12 offset:3072\n\t"            \
                     "global_load_dwordx4 %8, %10, %13"                           \
                     : "=&v"(TQ[0]), "=&v"(TQ[1]), "=&v"(TQ[2]), "=&v"(TQ[3]),    \
                       "=&v"(TQ[4]), "=&v"(TQ[5]), "=&v"(TQ[6]), "=&v"(TQ[7]),    \
                       "=&v"(EV)                                                  \
                     : "v"(vofft), "v"(voffe), "s"(t0_), "s"(t1_), "s"(eb_)       \
                     : "memory");                                                 \
    }

#define WAIT_TIE(TQ, EV)                                                          \
    asm volatile("s_waitcnt vmcnt(27)"                                            \
                 : "+v"(TQ[0]), "+v"(TQ[1]), "+v"(TQ[2]), "+v"(TQ[3]),            \
                   "+v"(TQ[4]), "+v"(TQ[5]), "+v"(TQ[6]), "+v"(TQ[7]),            \
                   "+v"(EV)                                                       \
                 :: "memory")

#define BPERM_REBUILD(P0, P1)                                                     \
    {                                                                             \
        v4i a0_, a1_;                                                             \
        a0_[0] = __builtin_amdgcn_ds_bpermute(idx0, P0);                          \
        a0_[1] = __builtin_amdgcn_ds_bpermute(idx1, P0);                          \
        a0_[2] = __builtin_amdgcn_ds_bpermute(idx2, P0);                          \
        a0_[3] = __builtin_amdgcn_ds_bpermute(idx3, P0);                          \
        a1_[0] = __builtin_amdgcn_ds_bpermute(idx0, P1);                          \
        a1_[1] = __builtin_amdgcn_ds_bpermute(idx1, P1);                          \
        a1_[2] = __builtin_amdgcn_ds_bpermute(idx2, P1);                          \
        a1_[3] = __builtin_amdgcn_ds_bpermute(idx3, P1);                          \
        af0 = bfrag(a0_); af1 = bfrag(a1_);                                       \
    }

#define MFMA8(TQ)                                                                 \
    v4f z4 = {0.f, 0.f, 0.f, 0.f};                                                \
    v4f d0 = MFMA16(af0, bfrag(TQ[0]), z4);                                       \
    v4f d1 = MFMA16(af0, bfrag(TQ[1]), z4);                                       \
    v4f d2 = MFMA16(af0, bfrag(TQ[2]), z4);                                       \
    v4f d3 = MFMA16(af0, bfrag(TQ[3]), z4);                                       \
    v4f f0 = MFMA16(af1, bfrag(TQ[4]), z4);                                       \
    v4f f1 = MFMA16(af1, bfrag(TQ[5]), z4);                                       \
    v4f f2 = MFMA16(af1, bfrag(TQ[6]), z4);                                       \
    v4f f3 = MFMA16(af1, bfrag(TQ[7]), z4);

#define COMPUTE_F(TQ, EV)                                                         \
    {                                                                             \
        MFMA8(TQ)                                                                 \
        float ei_ = inv;                                                          \
        float y0 = d0[0] + f0[0], y1 = d1[0] + f1[0];                             \
        float y2 = d2[0] + f2[0], y3 = d3[0] + f3[0];                             \
        zn0 = y0 * EV.x * ei_; zn1 = y1 * EV.y * ei_;                             \
        zn2 = y2 * EV.z * ei_; zn3 = y3 * EV.w * ei_;                             \
        int p0_ = pkh(zn0, zn1), p1_ = pkh(zn2, zn3);                             \
        BPERM_REBUILD(p0_, p1_)                                                   \
        lsacc -= (double)__log2f(ei_);                                            \
        float s_ = (zn0 + zn1) + (zn2 + zn3);                                     \
        DPP16_SUM(s_)                                                             \
        inv = fast_rcp(s_);                                                       \
    }

#define COMPUTE_B(TQ, EV)                                                         \
    {                                                                             \
        float ei_ = inv;                                                          \
        float w0 = zn0 * EV.x * ei_, w1 = zn1 * EV.y * ei_;                       \
        float w2 = zn2 * EV.z * ei_, w3 = zn3 * EV.w * ei_;                       \
        int p0_ = pkh(w0, w1), p1_ = pkh(w2, w3);                                 \
        BPERM_REBUILD(p0_, p1_)                                                   \
        MFMA8(TQ)                                                                 \
        zn0 = d0[0] + f0[0]; zn1 = d1[0] + f1[0];                                 \
        zn2 = d2[0] + f2[0]; zn3 = d3[0] + f3[0];                                 \
        lsacc -= (double)__log2f(ei_);                                            \
        float s_ = (w0 + w1) + (w2 + w3);                                         \
        DPP16_SUM(s_)                                                             \
        inv = fast_rcp(s_);                                                       \
    }

// ---------------- prep kernels (R13 proven) ----------------
__global__ __launch_bounds__(256) void prep_emit(const float* __restrict__ log_emit) {
    int idx = blockIdx.x * 256 + threadIdx.x;
    int v = idx >> 6;
    int j = idx & 63;
    gEmitT2[v * 64 + (j & 15) * 4 + (j >> 4)] = expf(log_emit[(j + 1) * HMM_V + v]);
}

__global__ __launch_bounds__(64) void prep_small(const float* __restrict__ log_trans,
                                                 const float* __restrict__ log_pi) {
    int j = threadIdx.x;
    for (int i = 0; i < 64; ++i)
        gET[i * 64 + j] = expf(log_trans[(i + 1) * HMM_S + (j + 1)]);
    float s = 0.f;
    for (int i = 0; i < HMM_S; ++i)
        s += expf(log_pi[i]) * expf(log_trans[i * HMM_S + (j + 1)]);
    gArow0[j] = s;
    float tc = log_trans[(j + 1) * HMM_S + 0];
    float mx = tc;
    for (int d = 1; d < 64; d <<= 1) mx = fmaxf(mx, __shfl_xor(mx, d));
    gTcs2[(j & 15) * 4 + (j >> 4)] = expf(tc - mx);
    if (j == 0) gTcmax = mx;
    for (int i = 0; i < 64; ++i) {
        int r, lane, sj;
        frag_pos(i, j, &r, &lane, &sj);
        gP1[(r * 64 + lane) * 8 + sj] = (__fp16)(gET[i * 64 + j] * 1024.0f);
    }
}

__global__ __launch_bounds__(256) void prep_table() {
    __shared__ float ETs[64 * 64];
    __shared__ float ETp[64 * 66];
    __shared__ float ev[64];
    __shared__ float wmax[4];
    __shared__ __attribute__((aligned(16))) __fp16 stage[4096];
    const int t = threadIdx.x;
    const int m = t & 63;
    const int seg = t >> 6;
    const int i0 = seg * 16;
    const int v = blockIdx.x;
    for (int i = i0; i < i0 + 16; ++i) ETs[i * 64 + m] = gET[i * 64 + m];
    for (int j = i0; j < i0 + 16; ++j) ETp[j * 66 + m] = gET[j * 64 + m];
    if (t < 64) ev[t] = gEmitT2[v * 64 + (t & 15) * 4 + (t >> 4)];
    __syncthreads();
    float acc[16];
#pragma unroll
    for (int q = 0; q < 16; ++q) acc[q] = 0.f;
    for (int j = 0; j < 64; ++j) {
        float w = ev[j] * ETp[j * 66 + m];
#pragma unroll
        for (int q = 0; q < 16; ++q) acc[q] = fmaf(ETs[(i0 + q) * 64 + j], w, acc[q]);
    }
    float mx = acc[0];
#pragma unroll
    for (int q = 1; q < 16; ++q) mx = fmaxf(mx, acc[q]);
    for (int d = 1; d < 64; d <<= 1) mx = fmaxf(mx, __shfl_xor(mx, d));
    if (m == 0) wmax[seg] = mx;
    __syncthreads();
    mx = fmaxf(fmaxf(wmax[0], wmax[1]), fmaxf(wmax[2], wmax[3]));
    int e;
    (void)frexpf(mx, &e);
    float sc = exp2f((float)(11 - e));
    if (t == 0) gSlog[v] = (float)(e - 11) * (float)LN2;
    for (int q = 0; q < 16; ++q) {
        int i = i0 + q;
        int r, lane, sj;
        frag_pos(i, m, &r, &lane, &sj);
        stage[(r * 64 + lane) * 8 + sj] = (__fp16)(acc[q] * sc);
    }
    __syncthreads();
    {
        int4* dst = (int4*)(gMtab + v * 4096);
        const int4* src = (const int4*)stage;
        for (int k = t; k < 512; k += 256) dst[k] = src[k];
    }
    __syncthreads();
    for (int q = 0; q < 16; ++q) {
        int i = i0 + q;
        int r, lane, sj;
        frag_pos(m, i, &r, &lane, &sj);
        stage[(r * 64 + lane) * 8 + sj] = (__fp16)(acc[q] * sc);
    }
    __syncthreads();
    {
        int4* dst = (int4*)(gMtabT + v * 4096);
        const int4* src = (const int4*)stage;
        for (int k = t; k < 512; k += 256) dst[k] = src[k];
    }
}

// ---------------- split-scan: 768 blocks = 128 batches x 6 runs ----------------
__global__ __launch_bounds__(64, 1) void hmm_scan(const int* __restrict__ obvs) {
    __shared__ __attribute__((aligned(16))) ushort4 obs4[520];  // 1024 words + guards
    __shared__ float a0lds[64];
    const int bid = blockIdx.x;
    const int rid = bid % 6;
    const int b = bid / 6;
    const int seg = (rid + 1) >> 1;           // 0,1,1,2,2,3
    const bool isf = (rid == 0) || (rid == 1) || (rid == 3);
    const int A0 = seg * 1024;                // segment base app
    const int lane = threadIdx.x;
    const uint* view = (const uint*)obs4;     // uint word = (obs[2a], obs[2a+1])

    // ---- stage this segment's obs quarter + slog sum ----
    float slsum = 0.f;
    {
        const int4* og = (const int4*)(obvs + b * HMM_T) + (A0 >> 1);
        if (isf) {
            for (int it = lane; it < 512; it += 64) {
                int4 o = og[it];
                obs4[it] = make_ushort4((unsigned short)o.x, (unsigned short)o.y,
                                        (unsigned short)o.z, (unsigned short)o.w);
                slsum += ((it == 0 && rid == 0) ? 0.f : gSlog[o.x]) + gSlog[o.z];
            }
            if (lane < 8) obs4[512 + lane] = make_ushort4(0, 0, 0, 0);  // words 1024..1039
        } else {
            for (int it = lane; it < 512; it += 64) {
                int4 o = og[it];
                obs4[it + 4] = make_ushort4((unsigned short)o.x, (unsigned short)o.y,
                                            (unsigned short)o.z, (unsigned short)o.w);
                slsum += gSlog[o.x] + gSlog[o.z];
            }
            if (lane < 4) obs4[lane] = make_ushort4(0, 0, 0, 0);  // guard words A0-8..A0-1
        }
    }
    __syncthreads();

    const int vofft = lane * 16;
    const int voffe = (lane & 15) * 16;
    const int idx0 = (lane >> 4) * 16;
    const int idx1 = idx0 + 4, idx2 = idx0 + 8, idx3 = idx0 + 12;

    double lsacc;
    float zn0, zn1, zn2, zn3;
    float inv = 1.0f;
    h8 af0, af1;

    v4i qa[8], qb[8], qc[8], qd[8];
    v4f ea, eb, ec, ed;

    if (isf) {
        // ---- fwd init ----
        if (rid == 0) {
            int o0 = obvs[b * HMM_T];
            float a0 = gArow0[lane] * gEmitT2[o0 * 64 + (lane & 15) * 4 + (lane >> 4)];
            float s0 = a0;
#pragma unroll
            for (int d = 1; d < 64; d <<= 1) s0 += __shfl_xor(s0, d);
            a0lds[lane] = a0 / s0;
            __syncthreads();
            lsacc = (double)__log2f(s0) - 10.0;  // -10 repays gP1's 2^10 scale
            const int g4 = (lane >> 4) * 4;
            v4i a0_, a1_;
#pragma unroll
            for (int ri = 0; ri < 4; ++ri) {
                a0_[ri] = pkh(a0lds[g4 + ri], a0lds[16 + g4 + ri]);
                a1_[ri] = pkh(a0lds[32 + g4 + ri], a0lds[48 + g4 + ri]);
            }
            af0 = bfrag(a0_);
            af1 = bfrag(a1_);
        } else {
            // start from ones/64 (sum 1); e^L*stored = P_seg(1): lsacc = +log2(64)
            int onep = pkh(0.015625f, 0.015625f);
            af0 = bfrag((v4i){onep, onep, onep, onep});
            af1 = bfrag((v4i){onep, onep, onep, onep});
            lsacc = 6.0;
        }
        zn0 = zn1 = zn2 = zn3 = 0.f;

        // ---- prologue: apps A0..A0+3 ----
        if (rid == 0) {
            ISSUE_APP(qa, ea, view[0] & 0xFFFF0000u, gP1)  // app0: P1, v1 forced 0
        } else {
            ISSUE_APP(qa, ea, view[0], gMtab)
        }
        ISSUE_APP(qb, eb, view[1], gMtab)
        ISSUE_APP(qc, ec, view[2], gMtab)
        ISSUE_APP(qd, ed, view[3], gMtab)
        uint o0p = view[4], o1p = view[5], o2p = view[6], o3p = view[7];

        for (int g = 0; g < 256; ++g) {
            const int base = 4 * g;
            WAIT_TIE(qa, ea);
            COMPUTE_F(qa, ea)
            ISSUE_APP(qa, ea, o0p, gMtab)
            o0p = view[base + 8];
            WAIT_TIE(qb, eb);
            COMPUTE_F(qb, eb)
            ISSUE_APP(qb, eb, o1p, gMtab)
            o1p = view[base + 9];
            WAIT_TIE(qc, ec);
            COMPUTE_F(qc, ec)
            ISSUE_APP(qc, ec, o2p, gMtab)
            o2p = view[base + 10];
            WAIT_TIE(qd, ed);
            COMPUTE_F(qd, ed)
            ISSUE_APP(qd, ed, o3p, gMtab)
            o3p = view[base + 11];
        }
        asm volatile("s_waitcnt vmcnt(0)" ::: "memory");
    } else {
        // ---- bwd init ----
        if (rid == 5) {
            const float4 tc4 = *(const float4*)(gTcs2 + (lane & 15) * 4);
            zn0 = tc4.x * 1024.0f; zn1 = tc4.y * 1024.0f;
            zn2 = tc4.z * 1024.0f; zn3 = tc4.w * 1024.0f;
            lsacc = -10.0;
        } else {
            // start from 16*ones; e^L*stored = P_seg^T(1): lsacc = -log2(16)
            zn0 = zn1 = zn2 = zn3 = 16.0f;
            lsacc = -4.0;
        }
        // view index for word w: w - (A0 - 8); guards cover A0-8..A0-1
#define VB(W) view[(W) - A0 + 8]
        const int At = A0 + 1023;
        ISSUE_APP(qa, ea, VB(At), gMtabT)
        ISSUE_APP(qb, eb, VB(At - 1), gMtabT)
        ISSUE_APP(qc, ec, VB(At - 2), gMtabT)
        ISSUE_APP(qd, ed, VB(At - 3), gMtabT)
        uint o0p = VB(At - 4), o1p = VB(At - 5), o2p = VB(At - 6), o3p = VB(At - 7);

        for (int g = 0; g < 256; ++g) {
            const int base = At - 4 * g;
            WAIT_TIE(qa, ea);
            COMPUTE_B(qa, ea)
            ISSUE_APP(qa, ea, o0p, gMtabT)
            o0p = VB(base - 8);
            WAIT_TIE(qb, eb);
            COMPUTE_B(qb, eb)
            ISSUE_APP(qb, eb, o1p, gMtabT)
            o1p = VB(base - 9);
            WAIT_TIE(qc, ec);
            COMPUTE_B(qc, ec)
            ISSUE_APP(qc, ec, o2p, gMtabT)
            o2p = VB(base - 10);
            WAIT_TIE(qd, ed);
            COMPUTE_B(qd, ed)
            ISSUE_APP(qd, ed, o3p, gMtabT)
            o3p = VB(base - 11);
        }
        asm volatile("s_waitcnt vmcnt(0)" ::: "memory");
#undef VB
    }

    // ---- store vec + log ----
#pragma unroll
    for (int d = 1; d < 64; d <<= 1) slsum += __shfl_xor(slsum, d);
    if (lane < 16) {
        float* vp = gVecs + (b * 6 + rid) * 64 + lane * 4;
        vp[0] = zn0; vp[1] = zn1; vp[2] = zn2; vp[3] = zn3;
    }
    if (lane == 0) gLs[b * 6 + rid] = (double)slsum + lsacc * LN2;
}

// ---------------- combine ----------------
// log L = L0 + L1 + L3 + L5 + log(V1.F0) + log(V2.U1) + log(G.U2)
//         - log(sum V1) - log(sum V2) + tcmax
__global__ __launch_bounds__(64) void hmm_combine(float* __restrict__ out) {
    const int b = blockIdx.x;
    const int lane = threadIdx.x;
    const float* V = gVecs + b * 6 * 64;
    float f0 = V[0 * 64 + lane], u1 = V[1 * 64 + lane], v1 = V[2 * 64 + lane];
    float u2 = V[3 * 64 + lane], v2 = V[4 * 64 + lane], gg = V[5 * 64 + lane];
    float d1 = v1 * f0;   // V1 . F0
    float c1 = v1;        // sum V1
    float d2 = v2 * u1;   // V2 . U1
    float c2 = v2;        // sum V2
    float d3 = gg * u2;   // G . U2
#pragma unroll
    for (int d = 1; d < 64; d <<= 1) {
        d1 += __shfl_xor(d1, d);
        c1 += __shfl_xor(c1, d);
        d2 += __shfl_xor(d2, d);
        c2 += __shfl_xor(c2, d);
        d3 += __shfl_xor(d3, d);
    }
    if (lane == 0) {
        const double* L = gLs + b * 6;
        double r = L[0] + L[1] + L[3] + L[5] + (double)gTcmax;
        r += log((double)d1) + log((double)d2) + log((double)d3);
        r -= log((double)c1) + log((double)c2);
        out[b] = (float)r;
    }
}

// ---------------- launch ----------------
extern "C" void kernel_launch(void* const* d_in, const int* in_sizes, int n_in,
                              void* d_out, int out_size, void* d_ws, size_t ws_size,
                              hipStream_t stream) {
    const float* log_trans = (const float*)d_in[0];  // 65*65
    const float* log_emit  = (const float*)d_in[1];  // 65*1024
    const float* log_pi    = (const float*)d_in[2];  // 65
    const int*   obvs      = (const int*)d_in[3];    // 128*8192
    float* out = (float*)d_out;

    prep_emit<<<256, 256, 0, stream>>>(log_emit);
    prep_small<<<1, 64, 0, stream>>>(log_trans, log_pi);
    prep_table<<<1024, 256, 0, stream>>>();
    hmm_scan<<<6 * HMM_B, 64, 0, stream>>>(obvs);
    hmm_combine<<<HMM_B, 64, 0, stream>>>(out);
}

// Round 15
// 399.293 us; speedup vs baseline: 1.9287x; 1.9287x over previous
//
#include <hip/hip_runtime.h>
#include <hip/hip_bf16.h>
#include <stdint.h>

// HMM batched forward, B=128, T=8192, S=65 (state 0 = bookend dead after init), V=1024.
//
// R15: unfused ET-resident scan. R14 post-mortem: scan is per-CU VMEM-throughput
// bound (~16 B/cy/CU; one 8KB fused-table app per ~512 cyc, invariant to wave
// count). Fix: keep ET in 32 persistent VGPRs (B-frag, proven self-labeled
// layout, x16 scale) and compute each app unfused:
//   MFMA(ET) -> x e_v1 (C-layout) -> bpermute rebuild -> MFMA(ET) -> x e_v2
//   -> stale-inv renorm.
// Per-app fetch: 512 B (two f32 emission rows) instead of 8 KB -> BW wall gone.
// Q=4 forward-only segments of 1024 apps (512 blocks = 128 batches x 4, 2/CU);
// segments q>0 start from uniform with 96-app burn-in (contraction; R14
// validated rank-1 collapse over 1024 apps end-to-end). Counted-window log:
// lsacc reset to +log2(inv_pending) at the burn-in boundary cancels the
// spurious first term; non-final segments add the pending last term; ET's
// 16x/stage repaid as exact constant (8/app; seg0's half-app: 4).
// No fused tables -> prep_table deleted entirely. All MFMA/bpermute/C-layout
// machinery is R13-proven verbatim; zero new layout assumptions.

#define HMM_B 128
#define HMM_T 8192
#define HMM_S 65
#define HMM_V 1024
#define LN2 0.6931471805599453
#define W_BURN 96

typedef _Float16 h8 __attribute__((ext_vector_type(8)));
typedef int    v4i __attribute__((ext_vector_type(4)));
typedef float  v4f __attribute__((ext_vector_type(4)));
typedef unsigned int uint;

// ---------------- device-global tables ----------------
__device__ __attribute__((aligned(16))) __fp16 gETB[4096];           // ET in B-frag, x16
__device__ __attribute__((aligned(16))) float  gEmitT2[HMM_V * 64];  // [v][c*4+u] = e_v[16u+c]
__device__ __attribute__((aligned(16))) float gArow0[64];
__device__ __attribute__((aligned(16))) float gTcs2[64];  // [c*4+u] = exp(tcol[16u+c]-tcmax)
__device__ float gTcmax;
// handoff
__device__ __attribute__((aligned(16))) float gVec[HMM_B * 64];  // seg3 final state
__device__ double gLs[HMM_B * 4];

// frag-position (proven): value X[i][n] -> (r, lane, slot j)
__device__ __forceinline__ void frag_pos(int i, int n, int* r, int* lane, int* j) {
    int t = i >> 5, up = (i >> 4) & 1, g = (i & 15) >> 2, q = i & 3;
    *r = t * 4 + (n >> 4);
    *lane = g * 16 + (n & 15);
    *j = 2 * q + up;
}

// ---------------- helpers ----------------
template <int CTRL>
__device__ __forceinline__ float dpp_add(float x) {
    return x + __int_as_float(__builtin_amdgcn_update_dpp(
                   0, __float_as_int(x), CTRL, 0xF, 0xF, true));
}
#define DPP16_SUM(S)            \
    S = dpp_add<0xB1>(S);       \
    S = dpp_add<0x4E>(S);       \
    S = dpp_add<0x141>(S);      \
    S = dpp_add<0x128>(S);

__device__ __forceinline__ float fast_rcp(float x) {
#if __has_builtin(__builtin_amdgcn_rcpf)
    return __builtin_amdgcn_rcpf(x);
#else
    return 1.0f / x;
#endif
}

__device__ __forceinline__ h8 bfrag(v4i q) { return __builtin_bit_cast(h8, q); }
__device__ __forceinline__ int pkh(float a, float b) {
    return __builtin_bit_cast(int, __builtin_amdgcn_cvt_pkrtz(a, b));
}

#define MFMA16(A, B, C) __builtin_amdgcn_mfma_f32_16x16x32_f16((A), (B), (C), 0, 0, 0)

// 8 MFMA on persistent ET, replicated-A trick; yields y[n] replicated (reg 0)
#define MFMA8Y(TQ, Y0, Y1, Y2, Y3)                                                \
    {                                                                             \
        v4f z4 = {0.f, 0.f, 0.f, 0.f};                                            \
        v4f d0 = MFMA16(af0, bfrag(TQ[0]), z4);                                   \
        v4f d1 = MFMA16(af0, bfrag(TQ[1]), z4);                                   \
        v4f d2 = MFMA16(af0, bfrag(TQ[2]), z4);                                   \
        v4f d3 = MFMA16(af0, bfrag(TQ[3]), z4);                                   \
        v4f f0 = MFMA16(af1, bfrag(TQ[4]), z4);                                   \
        v4f f1 = MFMA16(af1, bfrag(TQ[5]), z4);                                   \
        v4f f2 = MFMA16(af1, bfrag(TQ[6]), z4);                                   \
        v4f f3 = MFMA16(af1, bfrag(TQ[7]), z4);                                   \
        Y0 = d0[0] + f0[0]; Y1 = d1[0] + f1[0];                                   \
        Y2 = d2[0] + f2[0]; Y3 = d3[0] + f3[0];                                   \
    }

#define BPERM_REBUILD(P0, P1)                                                     \
    {                                                                             \
        v4i a0_, a1_;                                                             \
        a0_[0] = __builtin_amdgcn_ds_bpermute(idx0, P0);                          \
        a0_[1] = __builtin_amdgcn_ds_bpermute(idx1, P0);                          \
        a0_[2] = __builtin_amdgcn_ds_bpermute(idx2, P0);                          \
        a0_[3] = __builtin_amdgcn_ds_bpermute(idx3, P0);                          \
        a1_[0] = __builtin_amdgcn_ds_bpermute(idx0, P1);                          \
        a1_[1] = __builtin_amdgcn_ds_bpermute(idx1, P1);                          \
        a1_[2] = __builtin_amdgcn_ds_bpermute(idx2, P1);                          \
        a1_[3] = __builtin_amdgcn_ds_bpermute(idx3, P1);                          \
        af0 = bfrag(a0_); af1 = bfrag(a1_);                                       \
    }

// full app = 2 HMM steps: stale inv applied at stage 1
#define COMPUTE_FULL(E1, E2)                                                      \
    {                                                                             \
        float ei_ = inv;                                                          \
        float t0_, t1_, t2_, t3_;                                                 \
        MFMA8Y(tET, t0_, t1_, t2_, t3_)                                           \
        t0_ *= (E1).x * ei_; t1_ *= (E1).y * ei_;                                 \
        t2_ *= (E1).z * ei_; t3_ *= (E1).w * ei_;                                 \
        int p0_ = pkh(t0_, t1_), p1_ = pkh(t2_, t3_);                             \
        BPERM_REBUILD(p0_, p1_)                                                   \
        MFMA8Y(tET, zn0, zn1, zn2, zn3)                                           \
        zn0 *= (E2).x; zn1 *= (E2).y; zn2 *= (E2).z; zn3 *= (E2).w;               \
        int q0_ = pkh(zn0, zn1), q1_ = pkh(zn2, zn3);                             \
        BPERM_REBUILD(q0_, q1_)                                                   \
        lsacc -= (double)__log2f(ei_);                                            \
        float s_ = (zn0 + zn1) + (zn2 + zn3);                                     \
        DPP16_SUM(s_)                                                             \
        inv = fast_rcp(s_);                                                       \
    }

// half app (seg0 app0: single step, inv == 1)
#define COMPUTE_HALF(E2)                                                          \
    {                                                                             \
        MFMA8Y(tET, zn0, zn1, zn2, zn3)                                           \
        zn0 *= (E2).x; zn1 *= (E2).y; zn2 *= (E2).z; zn3 *= (E2).w;               \
        int q0_ = pkh(zn0, zn1), q1_ = pkh(zn2, zn3);                             \
        BPERM_REBUILD(q0_, q1_)                                                   \
        float s_ = (zn0 + zn1) + (zn2 + zn3);                                     \
        DPP16_SUM(s_)                                                             \
        inv = fast_rcp(s_);                                                       \
    }

// ring: 2 emission loads per app (dwordx4 each)
#define ISSUE_E(E1, E2, W)                                                        \
    {                                                                             \
        uint w_ = (W);                                                            \
        uint u_ = (uint)__builtin_amdgcn_readfirstlane((int)w_);                  \
        const float* e1_ = gEmitT2 + (size_t)(u_ & 0xFFFFu) * 64u;                \
        const float* e2_ = gEmitT2 + (size_t)(u_ >> 16) * 64u;                    \
        asm volatile("global_load_dwordx4 %0, %2, %3\n\t"                         \
                     "global_load_dwordx4 %1, %2, %4"                             \
                     : "=&v"(E1), "=&v"(E2)                                       \
                     : "v"(voffe), "s"(e1_), "s"(e2_)                             \
                     : "memory");                                                 \
    }

#define WAIT_E(E1, E2)                                                            \
    asm volatile("s_waitcnt vmcnt(6)" : "+v"(E1), "+v"(E2) :: "memory")

#define PHASE(E1, E2, OBP, NEXTW)                                                 \
    WAIT_E(E1, E2);                                                               \
    COMPUTE_FULL(E1, E2)                                                          \
    ISSUE_E(E1, E2, OBP)                                                          \
    OBP = NEXTW;

// ---------------- prep kernels ----------------
__global__ __launch_bounds__(256) void prep_emit(const float* __restrict__ log_emit) {
    int idx = blockIdx.x * 256 + threadIdx.x;
    int v = idx >> 6;
    int j = idx & 63;
    gEmitT2[v * 64 + (j & 15) * 4 + (j >> 4)] = expf(log_emit[(j + 1) * HMM_V + v]);
}

__global__ __launch_bounds__(64) void prep_small(const float* __restrict__ log_trans,
                                                 const float* __restrict__ log_pi) {
    int j = threadIdx.x;  // live state j (output column)
    for (int i = 0; i < 64; ++i) {
        float et = expf(log_trans[(i + 1) * HMM_S + (j + 1)]);
        int r, lane, sj;
        frag_pos(i, j, &r, &lane, &sj);
        gETB[(r * 64 + lane) * 8 + sj] = (__fp16)(et * 16.0f);  // x16: f16-normal range
    }
    float s = 0.f;
    for (int i = 0; i < HMM_S; ++i)
        s += expf(log_pi[i]) * expf(log_trans[i * HMM_S + (j + 1)]);
    gArow0[j] = s;
    float tc = log_trans[(j + 1) * HMM_S + 0];
    float mx = tc;
    for (int d = 1; d < 64; d <<= 1) mx = fmaxf(mx, __shfl_xor(mx, d));
    gTcs2[(j & 15) * 4 + (j >> 4)] = expf(tc - mx);
    if (j == 0) gTcmax = mx;
}

// ---------------- scan: 512 blocks = 128 batches x 4 fwd segments ----------------
__global__ __launch_bounds__(64, 1) void hmm_scan(const int* __restrict__ obvs) {
    __shared__ __attribute__((aligned(16))) ushort4 obs4[564];  // up to 560 int4 + 4 guard
    __shared__ float a0lds[64];
    const int bid = blockIdx.x;
    const int q = bid & 3;
    const int b = bid >> 2;
    const int lane = threadIdx.x;
    const uint* view = (const uint*)obs4;  // word a = (obs[2a], obs[2a+1])

    const int AstartFull = (q == 0) ? 0 : q * 1024 - W_BURN;
    const int n4 = (q == 0) ? 512 : 560;  // int4 staged
#define VW(W) view[(W) - AstartFull]

    // ---- stage obs words [AstartFull, q*1024+1024) + guards ----
    {
        const int4* og = (const int4*)(obvs + b * HMM_T) + (AstartFull >> 1);
        ushort4* ow = obs4;
        for (int it = lane; it < n4; it += 64) {
            int4 o = og[it];
            ow[it] = make_ushort4((unsigned short)o.x, (unsigned short)o.y,
                                  (unsigned short)o.z, (unsigned short)o.w);
        }
        if (lane < 4) ow[n4 + lane] = make_ushort4(0, 0, 0, 0);
    }

    const int voffe = (lane & 15) * 16;  // emission float4 byte offset
    const int idx0 = (lane >> 4) * 16;   // bpermute byte indices (proven)
    const int idx1 = idx0 + 4, idx2 = idx0 + 8, idx3 = idx0 + 12;

    double lsacc = 0.0;
    float zn0 = 0.f, zn1 = 0.f, zn2 = 0.f, zn3 = 0.f;
    float inv = 1.0f;
    h8 af0, af1;

    if (q == 0) {
        // exact alpha0 init (incl. bookend), normalized, packed as A-frag
        int o0 = obvs[b * HMM_T];
        float a0 = gArow0[lane] * gEmitT2[o0 * 64 + (lane & 15) * 4 + (lane >> 4)];
        float s0 = a0;
#pragma unroll
        for (int d = 1; d < 64; d <<= 1) s0 += __shfl_xor(s0, d);
        a0lds[lane] = a0 / s0;
        __syncthreads();
        lsacc = (double)__log2f(s0);
        const int g4 = (lane >> 4) * 4;
        v4i a0_, a1_;
#pragma unroll
        for (int ri = 0; ri < 4; ++ri) {
            a0_[ri] = pkh(a0lds[g4 + ri], a0lds[16 + g4 + ri]);
            a1_[ri] = pkh(a0lds[32 + g4 + ri], a0lds[48 + g4 + ri]);
        }
        af0 = bfrag(a0_);
        af1 = bfrag(a1_);
    } else {
        __syncthreads();  // staging visible
        // uniform start (mapping-invariant), burn-in will converge the direction
        int onep = pkh(0.015625f, 0.015625f);
        af0 = bfrag((v4i){onep, onep, onep, onep});
        af1 = bfrag((v4i){onep, onep, onep, onep});
    }

    // ---- persistent ET fragments (32 VGPRs) ----
    v4i tET[8];
    {
        const int4* tb = (const int4*)gETB;
#pragma unroll
        for (int r = 0; r < 8; ++r) {
            int4 t = tb[r * 64 + lane];
            tET[r] = (v4i){t.x, t.y, t.z, t.w};
        }
    }
    asm volatile("s_waitcnt vmcnt(0)"
                 : "+v"(tET[0]), "+v"(tET[1]), "+v"(tET[2]), "+v"(tET[3]),
                   "+v"(tET[4]), "+v"(tET[5]), "+v"(tET[6]), "+v"(tET[7])
                 :: "memory");

    int ringStart, groups, burnG;
    if (q == 0) {
        // ---- peel apps 0..3 (app0 = half app covering step t=1) ----
        {
            uint w0 = VW(0);
            v4f E2 = ((const v4f*)(gEmitT2 + (size_t)(w0 >> 16) * 64))[lane & 15];
            COMPUTE_HALF(E2)
        }
        for (int a = 1; a < 4; ++a) {
            uint w = VW(a);
            v4f E1 = ((const v4f*)(gEmitT2 + (size_t)(w & 0xFFFFu) * 64))[lane & 15];
            v4f E2 = ((const v4f*)(gEmitT2 + (size_t)(w >> 16) * 64))[lane & 15];
            COMPUTE_FULL(E1, E2)
        }
        asm volatile("s_waitcnt vmcnt(0)" ::: "memory");
        ringStart = 4; groups = 255; burnG = -1;
    } else {
        ringStart = AstartFull; groups = 280; burnG = W_BURN / 4;
    }

    // ---- ring: depth 4, 2 loads/app, wait vmcnt(6) ----
    v4f ea1, ea2, eb1, eb2, ec1, ec2, ed1, ed2;
    ISSUE_E(ea1, ea2, VW(ringStart + 0))
    ISSUE_E(eb1, eb2, VW(ringStart + 1))
    ISSUE_E(ec1, ec2, VW(ringStart + 2))
    ISSUE_E(ed1, ed2, VW(ringStart + 3))
    uint o0p = VW(ringStart + 4), o1p = VW(ringStart + 5);
    uint o2p = VW(ringStart + 6), o3p = VW(ringStart + 7);

    for (int g = 0; g < groups; ++g) {
        if (g == burnG) lsacc = (double)__log2f(inv);  // cancel spurious first term
        const int base = ringStart + 4 * g;
        PHASE(ea1, ea2, o0p, VW(base + 8))
        PHASE(eb1, eb2, o1p, VW(base + 9))
        PHASE(ec1, ec2, o2p, VW(base + 10))
        PHASE(ed1, ed2, o3p, VW(base + 11))
    }
    asm volatile("s_waitcnt vmcnt(0)" ::: "memory");

    // ---- segment log + handoff ----
    if (q != 3) lsacc -= (double)__log2f(inv);  // add last counted s
    // ET x16 scale repayment: 8/app (2 stages x log2(16)); seg0 app0 is 1 stage
    const double sub = (q == 0) ? 8188.0 : 8192.0;
    if (lane == 0) gLs[b * 4 + q] = (lsacc - sub) * LN2;
    if (q == 3 && lane < 16) {
        float* vp = gVec + b * 64 + lane * 4;
        vp[0] = zn0; vp[1] = zn1; vp[2] = zn2; vp[3] = zn3;
    }
#undef VW
}

// ---------------- combine: out[b] = sum Dlog_q + tcmax + log(zn_final . tau) ----------------
__global__ __launch_bounds__(64) void hmm_combine(float* __restrict__ out) {
    const int b = blockIdx.x;
    const int lane = threadIdx.x;
    float pr = gVec[b * 64 + lane] * gTcs2[lane];
#pragma unroll
    for (int d = 1; d < 64; d <<= 1) pr += __shfl_xor(pr, d);
    if (lane == 0) {
        const double* L = gLs + b * 4;
        out[b] = (float)(L[0] + L[1] + L[2] + L[3] + (double)gTcmax +
                         log((double)pr));
    }
}

// ---------------- launch ----------------
extern "C" void kernel_launch(void* const* d_in, const int* in_sizes, int n_in,
                              void* d_out, int out_size, void* d_ws, size_t ws_size,
                              hipStream_t stream) {
    const float* log_trans = (const float*)d_in[0];  // 65*65
    const float* log_emit  = (const float*)d_in[1];  // 65*1024
    const float* log_pi    = (const float*)d_in[2];  // 65
    const int*   obvs      = (const int*)d_in[3];    // 128*8192
    float* out = (float*)d_out;

    prep_emit<<<256, 256, 0, stream>>>(log_emit);
    prep_small<<<1, 64, 0, stream>>>(log_trans, log_pi);
    hmm_scan<<<4 * HMM_B, 64, 0, stream>>>(obvs);
    hmm_combine<<<HMM_B, 64, 0, stream>>>(out);
}

// Round 16
// 243.433 us; speedup vs baseline: 3.1636x; 1.6403x over previous
//
#include <hip/hip_runtime.h>
#include <hip/hip_bf16.h>
#include <stdint.h>

// HMM batched forward, B=128, T=8192, S=65 (state 0 = bookend dead after init), V=1024.
//
// R16 = R15 with Q: 4 -> 16. R15 post-mortem: scan is pure chain-latency-bound
// (733 cyc/app, per-wave busy ~9% scales linearly with waves/CU -> no CU
// contention at 2 waves/CU). Wall = serial_apps x 733 cyc, so shorten the
// serial chain: 16 fwd segments of 256 apps + 96-app burn-in (R15 validated
// burn-in at zero detectable error; output is bf16-ulp-floored at 256).
// 2048 blocks = 128 batches x 16 segments = 8 waves/CU (2/SIMD).
// Everything else verbatim from R15: ET resident in 32 VGPRs (proven B-frag,
// x16), unfused 2-stage apps (MFMA -> xE1 -> bperm -> MFMA -> xE2 -> renorm),
// 512B/app emission fetch via depth-4 ring (vmcnt(6)), counted-window log.
// prep_emit reads made coalesced (was 64-way strided).

#define HMM_B 128
#define HMM_T 8192
#define HMM_S 65
#define HMM_V 1024
#define LN2 0.6931471805599453
#define W_BURN 96
#define QSEG 16
#define SEGAPPS 256  // 4096 apps / 16 segments

typedef _Float16 h8 __attribute__((ext_vector_type(8)));
typedef int    v4i __attribute__((ext_vector_type(4)));
typedef float  v4f __attribute__((ext_vector_type(4)));
typedef unsigned int uint;

// ---------------- device-global tables ----------------
__device__ __attribute__((aligned(16))) __fp16 gETB[4096];           // ET in B-frag, x16
__device__ __attribute__((aligned(16))) float  gEmitT2[HMM_V * 64];  // [v][c*4+u] = e_v[16u+c]
__device__ __attribute__((aligned(16))) float gArow0[64];
__device__ __attribute__((aligned(16))) float gTcs2[64];  // [c*4+u] = exp(tcol[16u+c]-tcmax)
__device__ float gTcmax;
// handoff
__device__ __attribute__((aligned(16))) float gVec[HMM_B * 64];  // final segment state
__device__ double gLs[HMM_B * QSEG];

// frag-position (proven): value X[i][n] -> (r, lane, slot j)
__device__ __forceinline__ void frag_pos(int i, int n, int* r, int* lane, int* j) {
    int t = i >> 5, up = (i >> 4) & 1, g = (i & 15) >> 2, q = i & 3;
    *r = t * 4 + (n >> 4);
    *lane = g * 16 + (n & 15);
    *j = 2 * q + up;
}

// ---------------- helpers ----------------
template <int CTRL>
__device__ __forceinline__ float dpp_add(float x) {
    return x + __int_as_float(__builtin_amdgcn_update_dpp(
                   0, __float_as_int(x), CTRL, 0xF, 0xF, true));
}
#define DPP16_SUM(S)            \
    S = dpp_add<0xB1>(S);       \
    S = dpp_add<0x4E>(S);       \
    S = dpp_add<0x141>(S);      \
    S = dpp_add<0x128>(S);

__device__ __forceinline__ float fast_rcp(float x) {
#if __has_builtin(__builtin_amdgcn_rcpf)
    return __builtin_amdgcn_rcpf(x);
#else
    return 1.0f / x;
#endif
}

__device__ __forceinline__ h8 bfrag(v4i q) { return __builtin_bit_cast(h8, q); }
__device__ __forceinline__ int pkh(float a, float b) {
    return __builtin_bit_cast(int, __builtin_amdgcn_cvt_pkrtz(a, b));
}

#define MFMA16(A, B, C) __builtin_amdgcn_mfma_f32_16x16x32_f16((A), (B), (C), 0, 0, 0)

// 8 MFMA on persistent ET, replicated-A trick; yields y[n] replicated (reg 0)
#define MFMA8Y(TQ, Y0, Y1, Y2, Y3)                                                \
    {                                                                             \
        v4f z4 = {0.f, 0.f, 0.f, 0.f};                                            \
        v4f d0 = MFMA16(af0, bfrag(TQ[0]), z4);                                   \
        v4f d1 = MFMA16(af0, bfrag(TQ[1]), z4);                                   \
        v4f d2 = MFMA16(af0, bfrag(TQ[2]), z4);                                   \
        v4f d3 = MFMA16(af0, bfrag(TQ[3]), z4);                                   \
        v4f f0 = MFMA16(af1, bfrag(TQ[4]), z4);                                   \
        v4f f1 = MFMA16(af1, bfrag(TQ[5]), z4);                                   \
        v4f f2 = MFMA16(af1, bfrag(TQ[6]), z4);                                   \
        v4f f3 = MFMA16(af1, bfrag(TQ[7]), z4);                                   \
        Y0 = d0[0] + f0[0]; Y1 = d1[0] + f1[0];                                   \
        Y2 = d2[0] + f2[0]; Y3 = d3[0] + f3[0];                                   \
    }

#define BPERM_REBUILD(P0, P1)                                                     \
    {                                                                             \
        v4i a0_, a1_;                                                             \
        a0_[0] = __builtin_amdgcn_ds_bpermute(idx0, P0);                          \
        a0_[1] = __builtin_amdgcn_ds_bpermute(idx1, P0);                          \
        a0_[2] = __builtin_amdgcn_ds_bpermute(idx2, P0);                          \
        a0_[3] = __builtin_amdgcn_ds_bpermute(idx3, P0);                          \
        a1_[0] = __builtin_amdgcn_ds_bpermute(idx0, P1);                          \
        a1_[1] = __builtin_amdgcn_ds_bpermute(idx1, P1);                          \
        a1_[2] = __builtin_amdgcn_ds_bpermute(idx2, P1);                          \
        a1_[3] = __builtin_amdgcn_ds_bpermute(idx3, P1);                          \
        af0 = bfrag(a0_); af1 = bfrag(a1_);                                       \
    }

// full app = 2 HMM steps: stale inv applied at stage 1
#define COMPUTE_FULL(E1, E2)                                                      \
    {                                                                             \
        float ei_ = inv;                                                          \
        float t0_, t1_, t2_, t3_;                                                 \
        MFMA8Y(tET, t0_, t1_, t2_, t3_)                                           \
        t0_ *= (E1).x * ei_; t1_ *= (E1).y * ei_;                                 \
        t2_ *= (E1).z * ei_; t3_ *= (E1).w * ei_;                                 \
        int p0_ = pkh(t0_, t1_), p1_ = pkh(t2_, t3_);                             \
        BPERM_REBUILD(p0_, p1_)                                                   \
        MFMA8Y(tET, zn0, zn1, zn2, zn3)                                           \
        zn0 *= (E2).x; zn1 *= (E2).y; zn2 *= (E2).z; zn3 *= (E2).w;               \
        int q0_ = pkh(zn0, zn1), q1_ = pkh(zn2, zn3);                             \
        BPERM_REBUILD(q0_, q1_)                                                   \
        lsacc -= (double)__log2f(ei_);                                            \
        float s_ = (zn0 + zn1) + (zn2 + zn3);                                     \
        DPP16_SUM(s_)                                                             \
        inv = fast_rcp(s_);                                                       \
    }

// half app (seg0 app0: single step, inv == 1)
#define COMPUTE_HALF(E2)                                                          \
    {                                                                             \
        MFMA8Y(tET, zn0, zn1, zn2, zn3)                                           \
        zn0 *= (E2).x; zn1 *= (E2).y; zn2 *= (E2).z; zn3 *= (E2).w;               \
        int q0_ = pkh(zn0, zn1), q1_ = pkh(zn2, zn3);                             \
        BPERM_REBUILD(q0_, q1_)                                                   \
        float s_ = (zn0 + zn1) + (zn2 + zn3);                                     \
        DPP16_SUM(s_)                                                             \
        inv = fast_rcp(s_);                                                       \
    }

// ring: 2 emission loads per app (dwordx4 each)
#define ISSUE_E(E1, E2, W)                                                        \
    {                                                                             \
        uint w_ = (W);                                                            \
        uint u_ = (uint)__builtin_amdgcn_readfirstlane((int)w_);                  \
        const float* e1_ = gEmitT2 + (size_t)(u_ & 0xFFFFu) * 64u;                \
        const float* e2_ = gEmitT2 + (size_t)(u_ >> 16) * 64u;                    \
        asm volatile("global_load_dwordx4 %0, %2, %3\n\t"                         \
                     "global_load_dwordx4 %1, %2, %4"                             \
                     : "=&v"(E1), "=&v"(E2)                                       \
                     : "v"(voffe), "s"(e1_), "s"(e2_)                             \
                     : "memory");                                                 \
    }

#define WAIT_E(E1, E2)                                                            \
    asm volatile("s_waitcnt vmcnt(6)" : "+v"(E1), "+v"(E2) :: "memory")

#define PHASE(E1, E2, OBP, NEXTW)                                                 \
    WAIT_E(E1, E2);                                                               \
    COMPUTE_FULL(E1, E2)                                                          \
    ISSUE_E(E1, E2, OBP)                                                          \
    OBP = NEXTW;

// ---------------- prep kernels ----------------
__global__ __launch_bounds__(256) void prep_emit(const float* __restrict__ log_emit) {
    int tid = blockIdx.x * 256 + threadIdx.x;  // 0..65535
    int j = tid >> 10;      // live state 0..63 (wave-uniform)
    int v = tid & 1023;     // consecutive -> coalesced reads
    gEmitT2[v * 64 + (j & 15) * 4 + (j >> 4)] = expf(log_emit[(j + 1) * HMM_V + v]);
}

__global__ __launch_bounds__(64) void prep_small(const float* __restrict__ log_trans,
                                                 const float* __restrict__ log_pi) {
    int j = threadIdx.x;  // live state j (output column)
    for (int i = 0; i < 64; ++i) {
        float et = expf(log_trans[(i + 1) * HMM_S + (j + 1)]);
        int r, lane, sj;
        frag_pos(i, j, &r, &lane, &sj);
        gETB[(r * 64 + lane) * 8 + sj] = (__fp16)(et * 16.0f);  // x16: f16-normal range
    }
    float s = 0.f;
    for (int i = 0; i < HMM_S; ++i)
        s += expf(log_pi[i]) * expf(log_trans[i * HMM_S + (j + 1)]);
    gArow0[j] = s;
    float tc = log_trans[(j + 1) * HMM_S + 0];
    float mx = tc;
    for (int d = 1; d < 64; d <<= 1) mx = fmaxf(mx, __shfl_xor(mx, d));
    gTcs2[(j & 15) * 4 + (j >> 4)] = expf(tc - mx);
    if (j == 0) gTcmax = mx;
}

// ---------------- scan: 2048 blocks = 128 batches x 16 fwd segments ----------------
__global__ __launch_bounds__(64, 1) void hmm_scan(const int* __restrict__ obvs) {
    __shared__ __attribute__((aligned(16))) ushort4 obs4[184];  // up to 176 int4 + guards
    __shared__ float a0lds[64];
    const int bid = blockIdx.x;
    const int q = bid & (QSEG - 1);
    const int b = bid >> 4;
    const int lane = threadIdx.x;
    const uint* view = (const uint*)obs4;  // word a = (obs[2a], obs[2a+1])

    const int AstartFull = (q == 0) ? 0 : q * SEGAPPS - W_BURN;
    const int n4 = (q == 0) ? (SEGAPPS / 2) : ((SEGAPPS + W_BURN) / 2);
#define VW(W) view[(W) - AstartFull]

    // ---- stage obs words [AstartFull, (q+1)*SEGAPPS) + guards ----
    {
        const int4* og = (const int4*)(obvs + b * HMM_T) + (AstartFull >> 1);
        ushort4* ow = obs4;
        for (int it = lane; it < n4; it += 64) {
            int4 o = og[it];
            ow[it] = make_ushort4((unsigned short)o.x, (unsigned short)o.y,
                                  (unsigned short)o.z, (unsigned short)o.w);
        }
        if (lane < 4) ow[n4 + lane] = make_ushort4(0, 0, 0, 0);
    }

    const int voffe = (lane & 15) * 16;  // emission float4 byte offset
    const int idx0 = (lane >> 4) * 16;   // bpermute byte indices (proven)
    const int idx1 = idx0 + 4, idx2 = idx0 + 8, idx3 = idx0 + 12;

    double lsacc = 0.0;
    float zn0 = 0.f, zn1 = 0.f, zn2 = 0.f, zn3 = 0.f;
    float inv = 1.0f;
    h8 af0, af1;

    if (q == 0) {
        // exact alpha0 init (incl. bookend), normalized, packed as A-frag
        int o0 = obvs[b * HMM_T];
        float a0 = gArow0[lane] * gEmitT2[o0 * 64 + (lane & 15) * 4 + (lane >> 4)];
        float s0 = a0;
#pragma unroll
        for (int d = 1; d < 64; d <<= 1) s0 += __shfl_xor(s0, d);
        a0lds[lane] = a0 / s0;
        __syncthreads();
        lsacc = (double)__log2f(s0);
        const int g4 = (lane >> 4) * 4;
        v4i a0_, a1_;
#pragma unroll
        for (int ri = 0; ri < 4; ++ri) {
            a0_[ri] = pkh(a0lds[g4 + ri], a0lds[16 + g4 + ri]);
            a1_[ri] = pkh(a0lds[32 + g4 + ri], a0lds[48 + g4 + ri]);
        }
        af0 = bfrag(a0_);
        af1 = bfrag(a1_);
    } else {
        __syncthreads();  // staging visible
        // uniform start (mapping-invariant); burn-in converges the direction
        int onep = pkh(0.015625f, 0.015625f);
        af0 = bfrag((v4i){onep, onep, onep, onep});
        af1 = bfrag((v4i){onep, onep, onep, onep});
    }

    // ---- persistent ET fragments (32 VGPRs) ----
    v4i tET[8];
    {
        const int4* tb = (const int4*)gETB;
#pragma unroll
        for (int r = 0; r < 8; ++r) {
            int4 t = tb[r * 64 + lane];
            tET[r] = (v4i){t.x, t.y, t.z, t.w};
        }
    }
    asm volatile("s_waitcnt vmcnt(0)"
                 : "+v"(tET[0]), "+v"(tET[1]), "+v"(tET[2]), "+v"(tET[3]),
                   "+v"(tET[4]), "+v"(tET[5]), "+v"(tET[6]), "+v"(tET[7])
                 :: "memory");

    int ringStart, groups, burnG;
    if (q == 0) {
        // ---- peel apps 0..3 (app0 = half app covering step t=1) ----
        {
            uint w0 = VW(0);
            v4f E2 = ((const v4f*)(gEmitT2 + (size_t)(w0 >> 16) * 64))[lane & 15];
            COMPUTE_HALF(E2)
        }
        for (int a = 1; a < 4; ++a) {
            uint w = VW(a);
            v4f E1 = ((const v4f*)(gEmitT2 + (size_t)(w & 0xFFFFu) * 64))[lane & 15];
            v4f E2 = ((const v4f*)(gEmitT2 + (size_t)(w >> 16) * 64))[lane & 15];
            COMPUTE_FULL(E1, E2)
        }
        asm volatile("s_waitcnt vmcnt(0)" ::: "memory");
        ringStart = 4; groups = (SEGAPPS - 4) / 4; burnG = -1;     // 63
    } else {
        ringStart = AstartFull; groups = (SEGAPPS + W_BURN) / 4;   // 88
        burnG = W_BURN / 4;                                        // 24
    }

    // ---- ring: depth 4, 2 loads/app, wait vmcnt(6) ----
    v4f ea1, ea2, eb1, eb2, ec1, ec2, ed1, ed2;
    ISSUE_E(ea1, ea2, VW(ringStart + 0))
    ISSUE_E(eb1, eb2, VW(ringStart + 1))
    ISSUE_E(ec1, ec2, VW(ringStart + 2))
    ISSUE_E(ed1, ed2, VW(ringStart + 3))
    uint o0p = VW(ringStart + 4), o1p = VW(ringStart + 5);
    uint o2p = VW(ringStart + 6), o3p = VW(ringStart + 7);

    for (int g = 0; g < groups; ++g) {
        if (g == burnG) lsacc = (double)__log2f(inv);  // cancel spurious first term
        const int base = ringStart + 4 * g;
        PHASE(ea1, ea2, o0p, VW(base + 8))
        PHASE(eb1, eb2, o1p, VW(base + 9))
        PHASE(ec1, ec2, o2p, VW(base + 10))
        PHASE(ed1, ed2, o3p, VW(base + 11))
    }
    asm volatile("s_waitcnt vmcnt(0)" ::: "memory");

    // ---- segment log + handoff ----
    if (q != QSEG - 1) lsacc -= (double)__log2f(inv);  // add last counted s
    // ET x16 repayment: 8/app (2 stages x log2 16); seg0 app0 is a single stage
    const double sub = (q == 0) ? (8.0 * SEGAPPS - 4.0) : (8.0 * SEGAPPS);
    if (lane == 0) gLs[b * QSEG + q] = (lsacc - sub) * LN2;
    if (q == QSEG - 1 && lane < 16) {
        float* vp = gVec + b * 64 + lane * 4;
        vp[0] = zn0; vp[1] = zn1; vp[2] = zn2; vp[3] = zn3;
    }
#undef VW
}

// ---------------- combine: out[b] = sum Dlog_q + tcmax + log(zn_final . tau) ----------------
__global__ __launch_bounds__(64) void hmm_combine(float* __restrict__ out) {
    const int b = blockIdx.x;
    const int lane = threadIdx.x;
    float pr = gVec[b * 64 + lane] * gTcs2[lane];
#pragma unroll
    for (int d = 1; d < 64; d <<= 1) pr += __shfl_xor(pr, d);
    if (lane == 0) {
        const double* L = gLs + b * QSEG;
        double acc = 0.0;
#pragma unroll
        for (int k = 0; k < QSEG; ++k) acc += L[k];
        out[b] = (float)(acc + (double)gTcmax + log((double)pr));
    }
}

// ---------------- launch ----------------
extern "C" void kernel_launch(void* const* d_in, const int* in_sizes, int n_in,
                              void* d_out, int out_size, void* d_ws, size_t ws_size,
                              hipStream_t stream) {
    const float* log_trans = (const float*)d_in[0];  // 65*65
    const float* log_emit  = (const float*)d_in[1];  // 65*1024
    const float* log_pi    = (const float*)d_in[2];  // 65
    const int*   obvs      = (const int*)d_in[3];    // 128*8192
    float* out = (float*)d_out;

    prep_emit<<<256, 256, 0, stream>>>(log_emit);
    prep_small<<<1, 64, 0, stream>>>(log_trans, log_pi);
    hmm_scan<<<QSEG * HMM_B, 64, 0, stream>>>(obvs);
    hmm_combine<<<HMM_B, 64, 0, stream>>>(out);
}

// Round 17
// 240.472 us; speedup vs baseline: 3.2026x; 1.0123x over previous
//
#include <hip/hip_runtime.h>
#include <hip/hip_bf16.h>
#include <stdint.h>

// HMM batched forward, B=128, T=8192, S=65 (state 0 = bookend dead after init), V=1024.
//
// R17: 16 real chains per wave via true A-rows. R16 post-mortem: replicated-A
// wastes 15/16 of each MFMA; pipes at 86% -> batch 16 batches' alpha vectors as
// the 16 A rows (doc-measured m120 row map m=lane&15; k slots keep our
// end-to-end-proven placement x(g,j), which is pairing-invariant). B = resident
// tET (proven). C-layout (proven): lane holds chains (lane>>4)*4+r at states
// 16u+(lane&15). C->A conversion via LDS round-trip (4x b64 write, 2x b128
// read; single wave, in-order DS pipe). Per-chain emissions per-lane loaded
// through the proven asm prefetch ring (8 x dwordx4/app, depth 2, vmcnt(8)).
// Per-chain renorm: DPP16 per reg; stale-inv + counted-window log per chain
// (f32 lsacc), exactly the R15/16-verified bookkeeping. Q=32 segments of 128
// apps + 96-app burn-in -> 224 serial apps, 256 blocks = 1 wave/CU.

#define HMM_B 128
#define HMM_T 8192
#define HMM_S 65
#define HMM_V 1024
#define LN2 0.6931471805599453
#define W_BURN 96
#define QSEG 32
#define SEGAPPS 128
#define NB 16
#define OPITCH 228

typedef _Float16 h8 __attribute__((ext_vector_type(8)));
typedef int    v4i __attribute__((ext_vector_type(4)));
typedef float  v4f __attribute__((ext_vector_type(4)));
typedef unsigned int uint;

// ---------------- device-global tables ----------------
__device__ __attribute__((aligned(16))) __fp16 gETB[4096];           // ET B-frag, x16
__device__ __attribute__((aligned(16))) float  gEmitT2[HMM_V * 64];  // [v][col*4+u] = e_v[16u+col]
__device__ __attribute__((aligned(16))) float gArow2[64];            // [col*4+u] = arow0[16u+col]
__device__ __attribute__((aligned(16))) float gTcsN[64];             // natural: exp(tcol[s]-tcmax)
__device__ float gTcmax;
__device__ __attribute__((aligned(16))) float gVec[HMM_B * 64];      // final states, natural
__device__ __attribute__((aligned(16))) float gLsF[HMM_B * QSEG];

// frag-position (proven): value X[i][n] -> (r, lane, slot j) for the B operand
__device__ __forceinline__ void frag_pos(int i, int n, int* r, int* lane, int* j) {
    int t = i >> 5, up = (i >> 4) & 1, g = (i & 15) >> 2, q = i & 3;
    *r = t * 4 + (n >> 4);
    *lane = g * 16 + (n & 15);
    *j = 2 * q + up;
}

// ---------------- helpers ----------------
template <int CTRL>
__device__ __forceinline__ float dpp_add(float x) {
    return x + __int_as_float(__builtin_amdgcn_update_dpp(
                   0, __float_as_int(x), CTRL, 0xF, 0xF, true));
}
#define DPP16_SUM(S)            \
    S = dpp_add<0xB1>(S);       \
    S = dpp_add<0x4E>(S);       \
    S = dpp_add<0x141>(S);      \
    S = dpp_add<0x128>(S);

__device__ __forceinline__ float fast_rcp(float x) {
#if __has_builtin(__builtin_amdgcn_rcpf)
    return __builtin_amdgcn_rcpf(x);
#else
    return 1.0f / x;
#endif
}
__device__ __forceinline__ h8 bfrag(v4i q) { return __builtin_bit_cast(h8, q); }
__device__ __forceinline__ int pkh(float a, float b) {
    return __builtin_bit_cast(int, __builtin_amdgcn_cvt_pkrtz(a, b));
}
__device__ __forceinline__ v4f vs(v4f a, float s) {
    return (v4f){a[0] * s, a[1] * s, a[2] * s, a[3] * s};
}

#define MFMA16(A, B, C) __builtin_amdgcn_mfma_f32_16x16x32_f16((A), (B), (C), 0, 0, 0)

// 8 MFMA; A = af (16 real chain rows), B = resident tET. Yu[r] = chain (4g+r),
// state 16u+col (proven C layout).
#define MFMA_Y                                                  \
    {                                                           \
        v4f z4v = {0.f, 0.f, 0.f, 0.f};                         \
        v4f D0 = MFMA16(af0, bfrag(tET[0]), z4v);               \
        v4f D1 = MFMA16(af0, bfrag(tET[1]), z4v);               \
        v4f D2 = MFMA16(af0, bfrag(tET[2]), z4v);               \
        v4f D3 = MFMA16(af0, bfrag(tET[3]), z4v);               \
        v4f F0 = MFMA16(af1, bfrag(tET[4]), z4v);               \
        v4f F1 = MFMA16(af1, bfrag(tET[5]), z4v);               \
        v4f F2 = MFMA16(af1, bfrag(tET[6]), z4v);               \
        v4f F3 = MFMA16(af1, bfrag(tET[7]), z4v);               \
        Y0 = D0 + F0; Y1 = D1 + F1; Y2 = D2 + F2; Y3 = D3 + F3; \
    }

#define TRR(r) ((v4f){Y0[r], Y1[r], Y2[r], Y3[r]})

// C->A transform through LDS: write per chain c=4g+r at col; read chain m=col
// (= lane&15), cols 4g..4g+3. Single wave: DS pipe in-order, no barrier.
#define PACK_AF                                                                     \
    TTa[wr0] = make_uint2((uint)pkh(zr0[0], zr0[1]), (uint)pkh(zr0[2], zr0[3]));    \
    TTa[wr1] = make_uint2((uint)pkh(zr1[0], zr1[1]), (uint)pkh(zr1[2], zr1[3]));    \
    TTa[wr2] = make_uint2((uint)pkh(zr2[0], zr2[1]), (uint)pkh(zr2[2], zr2[3]));    \
    TTa[wr3] = make_uint2((uint)pkh(zr3[0], zr3[1]), (uint)pkh(zr3[2], zr3[3]));    \
    {                                                                               \
        uint4 qq0 = *(const uint4*)&TTa[rdi];                                       \
        uint4 qq1 = *(const uint4*)&TTa[rdi + 2];                                   \
        af0 = bfrag((v4i){(int)qq0.x, (int)qq0.z, (int)qq1.x, (int)qq1.z});         \
        af1 = bfrag((v4i){(int)qq0.y, (int)qq0.w, (int)qq1.y, (int)qq1.w});         \
    }

#define RENORM4(EI0, EI1, EI2, EI3)                                 \
    {                                                               \
        float s0_ = (zr0[0] + zr0[1]) + (zr0[2] + zr0[3]);          \
        float s1_ = (zr1[0] + zr1[1]) + (zr1[2] + zr1[3]);          \
        float s2_ = (zr2[0] + zr2[1]) + (zr2[2] + zr2[3]);          \
        float s3_ = (zr3[0] + zr3[1]) + (zr3[2] + zr3[3]);          \
        DPP16_SUM(s0_) DPP16_SUM(s1_) DPP16_SUM(s2_) DPP16_SUM(s3_) \
        lsacc0 -= __log2f(EI0); lsacc1 -= __log2f(EI1);             \
        lsacc2 -= __log2f(EI2); lsacc3 -= __log2f(EI3);             \
        inv0 = fast_rcp(s0_); inv1 = fast_rcp(s1_);                 \
        inv2 = fast_rcp(s2_); inv3 = fast_rcp(s3_);                 \
    }

// one app = 2 stages; stale inv applied at stage A (R15 semantics, per chain)
#define APP16(EE0, EE1, EE2, EE3, EE4, EE5, EE6, EE7)                 \
    {                                                                 \
        float ei0_ = inv0, ei1_ = inv1, ei2_ = inv2, ei3_ = inv3;     \
        {                                                             \
            v4f Y0, Y1, Y2, Y3;                                       \
            MFMA_Y                                                    \
            zr0 = TRR(0) * vs(EE0, ei0_);                             \
            zr1 = TRR(1) * vs(EE1, ei1_);                             \
            zr2 = TRR(2) * vs(EE2, ei2_);                             \
            zr3 = TRR(3) * vs(EE3, ei3_);                             \
        }                                                             \
        PACK_AF                                                       \
        {                                                             \
            v4f Y0, Y1, Y2, Y3;                                       \
            MFMA_Y                                                    \
            zr0 = TRR(0) * EE4;                                       \
            zr1 = TRR(1) * EE5;                                       \
            zr2 = TRR(2) * EE6;                                       \
            zr3 = TRR(3) * EE7;                                       \
        }                                                             \
        PACK_AF                                                       \
        RENORM4(ei0_, ei1_, ei2_, ei3_)                               \
    }

// half app (seg0 app0: one stage)
#define APP_HALF(EE0, EE1, EE2, EE3)                                  \
    {                                                                 \
        float ei0_ = inv0, ei1_ = inv1, ei2_ = inv2, ei3_ = inv3;     \
        {                                                             \
            v4f Y0, Y1, Y2, Y3;                                       \
            MFMA_Y                                                    \
            zr0 = TRR(0) * vs(EE0, ei0_);                             \
            zr1 = TRR(1) * vs(EE1, ei1_);                             \
            zr2 = TRR(2) * vs(EE2, ei2_);                             \
            zr3 = TRR(3) * vs(EE3, ei3_);                             \
        }                                                             \
        PACK_AF                                                       \
        RENORM4(ei0_, ei1_, ei2_, ei3_)                               \
    }

// issue one app's 8 emission loads (4 chains x 2 stages), per-lane addresses
#define ISSUE16(E0, E1, E2, E3, E4, E5, E6, E7, K)                                \
    {                                                                             \
        uint w0_ = obsw[cidx0 + (K)];                                             \
        uint w1_ = obsw[cidx1 + (K)];                                             \
        uint w2_ = obsw[cidx2 + (K)];                                             \
        uint w3_ = obsw[cidx3 + (K)];                                             \
        uint a10_ = (w0_ & 0xFFFFu) * 256u + colb;                                \
        uint a11_ = (w1_ & 0xFFFFu) * 256u + colb;                                \
        uint a12_ = (w2_ & 0xFFFFu) * 256u + colb;                                \
        uint a13_ = (w3_ & 0xFFFFu) * 256u + colb;                                \
        uint a20_ = (w0_ >> 16) * 256u + colb;                                    \
        uint a21_ = (w1_ >> 16) * 256u + colb;                                    \
        uint a22_ = (w2_ >> 16) * 256u + colb;                                    \
        uint a23_ = (w3_ >> 16) * 256u + colb;                                    \
        asm volatile("global_load_dwordx4 %0, %8, %16\n\t"                        \
                     "global_load_dwordx4 %1, %9, %16\n\t"                        \
                     "global_load_dwordx4 %2, %10, %16\n\t"                       \
                     "global_load_dwordx4 %3, %11, %16\n\t"                       \
                     "global_load_dwordx4 %4, %12, %16\n\t"                       \
                     "global_load_dwordx4 %5, %13, %16\n\t"                       \
                     "global_load_dwordx4 %6, %14, %16\n\t"                       \
                     "global_load_dwordx4 %7, %15, %16"                           \
                     : "=&v"(E0), "=&v"(E1), "=&v"(E2), "=&v"(E3),                \
                       "=&v"(E4), "=&v"(E5), "=&v"(E6), "=&v"(E7)                 \
                     : "v"(a10_), "v"(a11_), "v"(a12_), "v"(a13_),                \
                       "v"(a20_), "v"(a21_), "v"(a22_), "v"(a23_),                \
                       "s"((const float*)gEmitT2)                                 \
                     : "memory");                                                 \
    }

#define WAITVA(E0, E1, E2, E3, E4, E5, E6, E7)                                    \
    asm volatile("s_waitcnt vmcnt(8)"                                             \
                 : "+v"(E0), "+v"(E1), "+v"(E2), "+v"(E3),                        \
                   "+v"(E4), "+v"(E5), "+v"(E6), "+v"(E7)                         \
                 :: "memory")

// ---------------- prep kernels ----------------
__global__ __launch_bounds__(256) void prep_emit(const float* __restrict__ log_emit) {
    int tid = blockIdx.x * 256 + threadIdx.x;  // 0..65535
    int j = tid >> 10;      // live state 0..63 (wave-uniform)
    int v = tid & 1023;     // consecutive -> coalesced reads
    gEmitT2[v * 64 + (j & 15) * 4 + (j >> 4)] = expf(log_emit[(j + 1) * HMM_V + v]);
}

__global__ __launch_bounds__(64) void prep_small(const float* __restrict__ log_trans,
                                                 const float* __restrict__ log_pi) {
    int j = threadIdx.x;  // live state j (output column)
    for (int i = 0; i < 64; ++i) {
        float et = expf(log_trans[(i + 1) * HMM_S + (j + 1)]);
        int r, lane, sj;
        frag_pos(i, j, &r, &lane, &sj);
        gETB[(r * 64 + lane) * 8 + sj] = (__fp16)(et * 16.0f);  // x16 f16-normal range
    }
    float s = 0.f;
    for (int i = 0; i < HMM_S; ++i)
        s += expf(log_pi[i]) * expf(log_trans[i * HMM_S + (j + 1)]);
    gArow2[(j & 15) * 4 + (j >> 4)] = s;
    float tc = log_trans[(j + 1) * HMM_S + 0];
    float mx = tc;
    for (int d = 1; d < 64; d <<= 1) mx = fmaxf(mx, __shfl_xor(mx, d));
    gTcsN[j] = expf(tc - mx);
    if (j == 0) gTcmax = mx;
}

// ---------------- scan: 256 blocks = 8 batch-groups x 32 segments ----------------
__global__ __launch_bounds__(64, 1) void hmm_scan(const int* __restrict__ obvs) {
    __shared__ uint obsw[16 * OPITCH];                             // 14.6 KB obs words
    __shared__ __attribute__((aligned(16))) uint2 TTa[16 * 18];    // transform scratch
    const int bid = blockIdx.x;
    const int q = bid & (QSEG - 1);
    const int bg = bid >> 5;             // batch group 0..7 (chains = bg*16 + c)
    const int lane = threadIdx.x;
    const int g = lane >> 4;
    const int col = lane & 15;

    const int AstartFull = (q == 0) ? 0 : q * SEGAPPS - W_BURN;
    const int n4 = (q == 0) ? 64 : 112;  // int4 per chain
    const int nW = 2 * n4;               // words per chain

    // ---- stage obs words for 16 chains + 2 guard words each ----
    for (int c = 0; c < 16; ++c) {
        const int4* og = (const int4*)(obvs + (size_t)(bg * 16 + c) * HMM_T +
                                       (size_t)AstartFull * 2);
        for (int it = lane; it < n4; it += 64) {
            int4 o = og[it];
            obsw[c * OPITCH + 2 * it]     = ((uint)o.x & 0xFFFFu) | ((uint)o.y << 16);
            obsw[c * OPITCH + 2 * it + 1] = ((uint)o.z & 0xFFFFu) | ((uint)o.w << 16);
        }
        if (lane < 2) obsw[c * OPITCH + nW + lane] = 0;
    }
    __syncthreads();

    // per-lane constants
    const uint colb = (uint)col * 16u;          // emission byte offset
    const int colb4 = col * 4;                  // emission float offset
    const int cidx0 = (4 * g + 0) * OPITCH;
    const int cidx1 = (4 * g + 1) * OPITCH;
    const int cidx2 = (4 * g + 2) * OPITCH;
    const int cidx3 = (4 * g + 3) * OPITCH;
    const int wr0 = (4 * g + 0) * 18 + col;     // TT write slots (C convention)
    const int wr1 = (4 * g + 1) * 18 + col;
    const int wr2 = (4 * g + 2) * 18 + col;
    const int wr3 = (4 * g + 3) * 18 + col;
    const int rdi = col * 18 + 4 * g;           // TT read base (A convention, m=col)

    // ---- persistent ET fragments (32 VGPRs, proven) ----
    v4i tET[8];
    {
        const int4* tb = (const int4*)gETB;
#pragma unroll
        for (int r = 0; r < 8; ++r) {
            int4 t = tb[r * 64 + lane];
            tET[r] = (v4i){t.x, t.y, t.z, t.w};
        }
    }
    asm volatile("s_waitcnt vmcnt(0)"
                 : "+v"(tET[0]), "+v"(tET[1]), "+v"(tET[2]), "+v"(tET[3]),
                   "+v"(tET[4]), "+v"(tET[5]), "+v"(tET[6]), "+v"(tET[7])
                 :: "memory");

    float inv0 = 1.f, inv1 = 1.f, inv2 = 1.f, inv3 = 1.f;
    float lsacc0 = 0.f, lsacc1 = 0.f, lsacc2 = 0.f, lsacc3 = 0.f;
    v4f zr0, zr1, zr2, zr3;
    h8 af0, af1;

    int kStart, kEnd, burnK;
    if (q == 0) {
        // ---- exact alpha0 init per chain, normalized, then half app + app1 peel ----
        uint w00 = obsw[cidx0 + 0], w01 = obsw[cidx1 + 0];
        uint w02 = obsw[cidx2 + 0], w03 = obsw[cidx3 + 0];
        v4f A4 = *(const v4f*)(gArow2 + colb4);
        zr0 = A4 * *(const v4f*)(gEmitT2 + (size_t)(w00 & 0xFFFFu) * 64 + colb4);
        zr1 = A4 * *(const v4f*)(gEmitT2 + (size_t)(w01 & 0xFFFFu) * 64 + colb4);
        zr2 = A4 * *(const v4f*)(gEmitT2 + (size_t)(w02 & 0xFFFFu) * 64 + colb4);
        zr3 = A4 * *(const v4f*)(gEmitT2 + (size_t)(w03 & 0xFFFFu) * 64 + colb4);
        {
            float s0_ = (zr0[0] + zr0[1]) + (zr0[2] + zr0[3]);
            float s1_ = (zr1[0] + zr1[1]) + (zr1[2] + zr1[3]);
            float s2_ = (zr2[0] + zr2[1]) + (zr2[2] + zr2[3]);
            float s3_ = (zr3[0] + zr3[1]) + (zr3[2] + zr3[3]);
            DPP16_SUM(s0_) DPP16_SUM(s1_) DPP16_SUM(s2_) DPP16_SUM(s3_)
            float i0_ = fast_rcp(s0_), i1_ = fast_rcp(s1_);
            float i2_ = fast_rcp(s2_), i3_ = fast_rcp(s3_);
            lsacc0 = -__log2f(i0_); lsacc1 = -__log2f(i1_);
            lsacc2 = -__log2f(i2_); lsacc3 = -__log2f(i3_);
            zr0 = vs(zr0, i0_); zr1 = vs(zr1, i1_);
            zr2 = vs(zr2, i2_); zr3 = vs(zr3, i3_);
        }
        PACK_AF
        // half app (covers step t=1), E = e(obs[1]) = word0 hi; inv==1
        {
            v4f H0 = *(const v4f*)(gEmitT2 + (size_t)(w00 >> 16) * 64 + colb4);
            v4f H1 = *(const v4f*)(gEmitT2 + (size_t)(w01 >> 16) * 64 + colb4);
            v4f H2 = *(const v4f*)(gEmitT2 + (size_t)(w02 >> 16) * 64 + colb4);
            v4f H3 = *(const v4f*)(gEmitT2 + (size_t)(w03 >> 16) * 64 + colb4);
            APP_HALF(H0, H1, H2, H3)
        }
        // peeled app k=1 (direct loads)
        {
            uint w10 = obsw[cidx0 + 1], w11 = obsw[cidx1 + 1];
            uint w12 = obsw[cidx2 + 1], w13 = obsw[cidx3 + 1];
            v4f P0 = *(const v4f*)(gEmitT2 + (size_t)(w10 & 0xFFFFu) * 64 + colb4);
            v4f P1 = *(const v4f*)(gEmitT2 + (size_t)(w11 & 0xFFFFu) * 64 + colb4);
            v4f P2 = *(const v4f*)(gEmitT2 + (size_t)(w12 & 0xFFFFu) * 64 + colb4);
            v4f P3 = *(const v4f*)(gEmitT2 + (size_t)(w13 & 0xFFFFu) * 64 + colb4);
            v4f P4 = *(const v4f*)(gEmitT2 + (size_t)(w10 >> 16) * 64 + colb4);
            v4f P5 = *(const v4f*)(gEmitT2 + (size_t)(w11 >> 16) * 64 + colb4);
            v4f P6 = *(const v4f*)(gEmitT2 + (size_t)(w12 >> 16) * 64 + colb4);
            v4f P7 = *(const v4f*)(gEmitT2 + (size_t)(w13 >> 16) * 64 + colb4);
            APP16(P0, P1, P2, P3, P4, P5, P6, P7)
        }
        kStart = 2; kEnd = SEGAPPS; burnK = -1;
    } else {
        // uniform start; burn-in converges the direction
        zr0 = zr1 = zr2 = zr3 = (v4f){0.015625f, 0.015625f, 0.015625f, 0.015625f};
        PACK_AF
        kStart = 0; kEnd = SEGAPPS + W_BURN; burnK = W_BURN;
    }

    // ---- ring: depth 2 apps x 8 loads, wait vmcnt(8) ----
    v4f Ea0, Ea1, Ea2, Ea3, Ea4, Ea5, Ea6, Ea7;
    v4f Eb0, Eb1, Eb2, Eb3, Eb4, Eb5, Eb6, Eb7;
    ISSUE16(Ea0, Ea1, Ea2, Ea3, Ea4, Ea5, Ea6, Ea7, kStart)
    ISSUE16(Eb0, Eb1, Eb2, Eb3, Eb4, Eb5, Eb6, Eb7, kStart + 1)

    for (int a = kStart; a < kEnd; a += 2) {
        if (a == burnK) {  // cancel burn-in window (R15-verified mechanics, per chain)
            lsacc0 = __log2f(inv0); lsacc1 = __log2f(inv1);
            lsacc2 = __log2f(inv2); lsacc3 = __log2f(inv3);
        }
        WAITVA(Ea0, Ea1, Ea2, Ea3, Ea4, Ea5, Ea6, Ea7);
        APP16(Ea0, Ea1, Ea2, Ea3, Ea4, Ea5, Ea6, Ea7)
        ISSUE16(Ea0, Ea1, Ea2, Ea3, Ea4, Ea5, Ea6, Ea7, a + 2)
        WAITVA(Eb0, Eb1, Eb2, Eb3, Eb4, Eb5, Eb6, Eb7);
        APP16(Eb0, Eb1, Eb2, Eb3, Eb4, Eb5, Eb6, Eb7)
        ISSUE16(Eb0, Eb1, Eb2, Eb3, Eb4, Eb5, Eb6, Eb7, a + 3)
    }
    asm volatile("s_waitcnt vmcnt(0)" ::: "memory");

    // ---- segment logs + handoff ----
    if (q != QSEG - 1) {  // pending last counted sum
        lsacc0 -= __log2f(inv0); lsacc1 -= __log2f(inv1);
        lsacc2 -= __log2f(inv2); lsacc3 -= __log2f(inv3);
    }
    // ET x16 repayment: 4/stage; counted stages: q0 = 255, else 256
    const float subf = (q == 0) ? 1020.0f : 1024.0f;
    if (col == 0) {
        gLsF[(bg * 16 + 4 * g + 0) * QSEG + q] = (lsacc0 - subf) * (float)LN2;
        gLsF[(bg * 16 + 4 * g + 1) * QSEG + q] = (lsacc1 - subf) * (float)LN2;
        gLsF[(bg * 16 + 4 * g + 2) * QSEG + q] = (lsacc2 - subf) * (float)LN2;
        gLsF[(bg * 16 + 4 * g + 3) * QSEG + q] = (lsacc3 - subf) * (float)LN2;
    }
    if (q == QSEG - 1) {
        float* vp = gVec + (size_t)(bg * 16) * 64;
#pragma unroll
        for (int u = 0; u < 4; ++u) {
            vp[(4 * g + 0) * 64 + 16 * u + col] = zr0[u];
            vp[(4 * g + 1) * 64 + 16 * u + col] = zr1[u];
            vp[(4 * g + 2) * 64 + 16 * u + col] = zr2[u];
            vp[(4 * g + 3) * 64 + 16 * u + col] = zr3[u];
        }
    }
}

// ---------------- combine: out[b] = sum Dlog_q + tcmax + log(z_final . tau) ----------------
__global__ __launch_bounds__(64) void hmm_combine(float* __restrict__ out) {
    const int b = blockIdx.x;
    const int lane = threadIdx.x;
    float pr = gVec[b * 64 + lane] * gTcsN[lane];
#pragma unroll
    for (int d = 1; d < 64; d <<= 1) pr += __shfl_xor(pr, d);
    if (lane == 0) {
        double acc = 0.0;
#pragma unroll
        for (int k = 0; k < QSEG; ++k) acc += (double)gLsF[b * QSEG + k];
        out[b] = (float)(acc + (double)gTcmax + log((double)pr));
    }
}

// ---------------- launch ----------------
extern "C" void kernel_launch(void* const* d_in, const int* in_sizes, int n_in,
                              void* d_out, int out_size, void* d_ws, size_t ws_size,
                              hipStream_t stream) {
    const float* log_trans = (const float*)d_in[0];  // 65*65
    const float* log_emit  = (const float*)d_in[1];  // 65*1024
    const float* log_pi    = (const float*)d_in[2];  // 65
    const int*   obvs      = (const int*)d_in[3];    // 128*8192
    float* out = (float*)d_out;

    prep_emit<<<256, 256, 0, stream>>>(log_emit);
    prep_small<<<1, 64, 0, stream>>>(log_trans, log_pi);
    hmm_scan<<<QSEG * (HMM_B / NB), 64, 0, stream>>>(obvs);
    hmm_combine<<<HMM_B, 64, 0, stream>>>(out);
}